// Round 1
// baseline (1663.725 us; speedup 1.0000x reference)
//
#include <hip/hip_runtime.h>

// Gridding: B=64, N=65536 points, scales (64,64,64).
// One thread per point; 8 atomicAdds into the (B, 64^3) fp32 grid.

#define GRID_SX 64
#define GRID_SY 64
#define GRID_SZ 64
#define HALF_S  32

__global__ __launch_bounds__(256) void gridding_kernel(
    const float* __restrict__ pt,   // (B, N, 3) flat
    float* __restrict__ grid,       // (B, 64*64*64) flat, pre-zeroed
    int n_per_batch,                // N
    int total)                      // B*N
{
    int i = blockIdx.x * blockDim.x + threadIdx.x;
    if (i >= total) return;

    int b = i / n_per_batch;

    // Coalesced-ish: lane i reads bytes [12i, 12i+12)
    float px = pt[3 * i + 0] * (GRID_SX * 0.5f);
    float py = pt[3 * i + 1] * (GRID_SY * 0.5f);
    float pz = pt[3 * i + 2] * (GRID_SZ * 0.5f);

    // nz_mask: skip exactly-zero points (reference zeroes their weights)
    if (fabsf(px) + fabsf(py) + fabsf(pz) == 0.0f) return;

    float lx = floorf(px), ly = floorf(py), lz = floorf(pz);
    float fx = px - lx,    fy = py - ly,    fz = pz - lz;

    int ix = (int)lx + HALF_S;
    int iy = (int)ly + HALF_S;
    int iz = (int)lz + HALF_S;

    float wx[2] = {1.0f - fx, fx};
    float wy[2] = {1.0f - fy, fy};
    float wz[2] = {1.0f - fz, fz};

    int base_b = b * (GRID_SX * GRID_SY * GRID_SZ);

    #pragma unroll
    for (int di = 0; di < 2; ++di) {
        int xx = ix + di;
        if ((unsigned)xx >= GRID_SX) continue;
        #pragma unroll
        for (int dj = 0; dj < 2; ++dj) {
            int yy = iy + dj;
            if ((unsigned)yy >= GRID_SY) continue;
            int base_xy = base_b + (xx * GRID_SY + yy) * GRID_SZ;
            float wxy = wx[di] * wy[dj];
            #pragma unroll
            for (int dk = 0; dk < 2; ++dk) {
                int zz = iz + dk;
                if ((unsigned)zz >= GRID_SZ) continue;
                atomicAdd(&grid[base_xy + zz], wxy * wz[dk]);
            }
        }
    }
}

extern "C" void kernel_launch(void* const* d_in, const int* in_sizes, int n_in,
                              void* d_out, int out_size, void* d_ws, size_t ws_size,
                              hipStream_t stream) {
    const float* pt = (const float*)d_in[0];
    float* out = (float*)d_out;

    int total = in_sizes[0] / 3;          // B * N points
    const int n_per_batch = 65536;        // N

    // d_out is re-poisoned to 0xAA before every timed launch — zero it.
    hipMemsetAsync(out, 0, (size_t)out_size * sizeof(float), stream);

    int block = 256;
    int grid_blocks = (total + block - 1) / block;
    gridding_kernel<<<grid_blocks, block, 0, stream>>>(pt, out, n_per_batch, total);
}

// Round 2
// 264.884 us; speedup vs baseline: 6.2809x; 6.2809x over previous
//
#include <hip/hip_runtime.h>

// Gridding: B=64, N=65536 points, grid 64^3 per batch, fp32.
//
// Strategy (R2): exclusive-ownership LDS privatization.
//   - 1024 blocks = 64 batches x 16 x-slabs (4 planes each).
//   - Block owns cells with x in [x0, x0+3]; sub-grid 4*64*64 fp32 = 64 KiB LDS.
//   - Each block scans ALL 65536 points of its batch (reads are L2/L3-resident;
//     redundancy 16x is cheap) and LDS-atomicAdds only the corners whose x
//     falls in its slab. Every corner of every point is claimed by exactly one
//     block -> zero global atomics, flush is plain coalesced float4 stores,
//     and every output cell is written exactly once (no memset needed).

#define NPTS   65536
#define SLABW  4          // x-planes per block
#define SLABS  16         // 64 / SLABW
#define SUBN   (SLABW * 64 * 64)   // 16384 floats = 64 KiB

__global__ __launch_bounds__(1024) void gridding_slab(
    const float* __restrict__ pt,   // (B, N, 3)
    float* __restrict__ out)        // (B, 64*64*64)
{
    __shared__ float lds[SUBN];

    const int blk = blockIdx.x;
    const int b   = blk >> 4;          // batch
    const int x0  = (blk & 15) * SLABW;

    // zero the private sub-grid
    float4* l4 = (float4*)lds;
    #pragma unroll
    for (int i = threadIdx.x; i < SUBN / 4; i += 1024)
        l4[i] = make_float4(0.f, 0.f, 0.f, 0.f);
    __syncthreads();

    const float* p = pt + (size_t)b * NPTS * 3;

    for (int it = 0; it < NPTS / 1024; ++it) {
        int i = it * 1024 + threadIdx.x;
        float px = p[3 * i + 0] * 32.0f;
        float py = p[3 * i + 1] * 32.0f;
        float pz = p[3 * i + 2] * 32.0f;

        // nz_mask: reference zeroes weights for exactly-zero points
        if (fabsf(px) + fabsf(py) + fabsf(pz) == 0.0f) continue;

        float lx = floorf(px), ly = floorf(py), lz = floorf(pz);
        float fx = px - lx,    fy = py - ly,    fz = pz - lz;
        int ix = (int)lx + 32, iy = (int)ly + 32, iz = (int)lz + 32;

        float wx[2] = {1.0f - fx, fx};
        float wy[2] = {1.0f - fy, fy};
        float wz[2] = {1.0f - fz, fz};

        #pragma unroll
        for (int di = 0; di < 2; ++di) {
            int xl = (ix + di) - x0;               // slab-local x
            if ((unsigned)xl >= SLABW) continue;   // not my slab (or x OOB)
            #pragma unroll
            for (int dj = 0; dj < 2; ++dj) {
                int yy = iy + dj;
                if ((unsigned)yy >= 64u) continue;
                float wxy = wx[di] * wy[dj];
                int base = (xl * 64 + yy) * 64;
                #pragma unroll
                for (int dk = 0; dk < 2; ++dk) {
                    int zz = iz + dk;
                    if ((unsigned)zz >= 64u) continue;
                    atomicAdd(&lds[base + zz], wxy * wz[dk]);  // ds_add_f32
                }
            }
        }
    }
    __syncthreads();

    // flush: slab is a contiguous 16384-float chunk of the output
    float4* o4 = (float4*)(out + ((size_t)b * 64 + x0) * 4096);
    #pragma unroll
    for (int i = threadIdx.x; i < SUBN / 4; i += 1024)
        o4[i] = l4[i];
}

extern "C" void kernel_launch(void* const* d_in, const int* in_sizes, int n_in,
                              void* d_out, int out_size, void* d_ws, size_t ws_size,
                              hipStream_t stream) {
    const float* pt = (const float*)d_in[0];
    float* out = (float*)d_out;

    const int B = (in_sizes[0] / 3) / NPTS;   // 64

    // Every output cell is written exactly once by its owning block -> no memset.
    gridding_slab<<<B * SLABS, 1024, 0, stream>>>(pt, out);
}